// Round 4
// baseline (3810.821 us; speedup 1.0000x reference)
//
#include <hip/hip_runtime.h>
#include <stdint.h>

#define T_DIM 4096
#define N_DIM 32768
#define D_DIM 1024
#define QB 64
#define KB 32
#define KSPLIT 4
#define ITERS (N_DIM / KSPLIT / KB)   // 256 iterations per block
#define NKB_TOT (N_DIM / KB)          // 1024 key-blocks total

typedef _Float16 f16;
typedef _Float16 f16x8 __attribute__((ext_vector_type(8)));
typedef _Float16 f16x4 __attribute__((ext_vector_type(4)));
typedef _Float16 f16x2 __attribute__((ext_vector_type(2)));
typedef float f32x4 __attribute__((ext_vector_type(4)));
typedef float f32x2 __attribute__((ext_vector_type(2)));

// XOR bits 2-3 of k-index with q's bits 2-3: b128 Spart ops conflict-free
#define SWZ(q, k0) ((k0) ^ ((((q) >> 2) & 3) << 2))

struct __align__(16) Lds {
  float Spart[8][64][40];  // 80 KiB : per-dq-slice partial scores [dq][q][k swz]
  f16   P[64][40];         //  5 KiB : P[q][k]
  float srow[64];          // per-q rescale factor for this iter
  float linv[64];          // epilogue 1/l
};                         // ~87.5 KiB

// ---- precompute: E (fp32 row-major) -> E16 (fp16 row-major)
__global__ void e16_build(const float* __restrict__ E, f16* __restrict__ E16) {
  size_t i8 = (size_t)(blockIdx.x * 256 + threadIdx.x) * 8;
  float4 a = *(const float4*)(E + i8);
  float4 b = *(const float4*)(E + i8 + 4);
  f16x8 v = {(f16)a.x,(f16)a.y,(f16)a.z,(f16)a.w,
             (f16)b.x,(f16)b.y,(f16)b.z,(f16)b.w};
  *(f16x8*)(E16 + i8) = v;
}

// ---- precompute: W2[kb][d][k] = fp16(E[kb*32+k][d])  (key-major V tiles)
__global__ void w2_build(const float* __restrict__ E, f16* __restrict__ W2) {
  int kb = blockIdx.x >> 2;
  int dg = blockIdx.x & 3;
  int d  = dg * 256 + threadIdx.x;
  for (int kq = 0; kq < 4; ++kq) {
    int k0 = kq * 8;
    f16x8 v;
    #pragma unroll
    for (int j = 0; j < 8; ++j)
      v[j] = (f16)E[(size_t)(kb*32 + k0 + j) * D_DIM + d];
    *(f16x8*)(W2 + (size_t)kb * (D_DIM*KB) + (size_t)d*KB + k0) = v;
  }
}

// 1024 threads = 16 waves. QK^T: wave (dq = w&7, qh = w>>3) computes partial
// scores over d-slice dq*128 for q-subtiles {qh*2, qh*2+1}. PV: wave owns
// d-slice w*64. Frag maps (verified r1/r2): A row=lane&15, k=(lane>>4)*8+j;
// B col=lane&15; C row=4*(lane>>4)+r, col=lane&15.
__global__ __launch_bounds__(1024)
void cboe_attn(const float* __restrict__ X, const f16* __restrict__ E16,
               const f16* __restrict__ W2, f16* __restrict__ O16,
               float* __restrict__ ML)
{
  extern __shared__ char smem_raw[];
  Lds& L = *reinterpret_cast<Lds*>(smem_raw);
  const int tid  = threadIdx.x;
  const int lane = tid & 63;
  const int w    = tid >> 6;       // wave 0..15
  const int c    = lane & 15;
  const int g    = lane >> 4;      // 0..3
  const int dq   = w & 7;          // QK d-slice: dq*128
  const int qh   = w >> 3;         // QK q-half: qt in {qh*2, qh*2+1}
  const int wd   = w * 64;         // PV d-slice

  // T1 XCD-grouping: blocks land on XCD (blockIdx.x & 7) under the default
  // round-robin dispatch. Give each XCD a single ks key-stream so its 32
  // resident blocks share the per-iter 128 KB E16/W2 chunk in per-XCD L2.
  const int xcd   = blockIdx.x & 7;
  const int ks    = xcd >> 1;                        // 2 XCDs per ks quarter
  const int qtile = (xcd & 1) * 32 + (blockIdx.x >> 3);
  const int qb    = qtile * QB;
  const size_t key0 = (size_t)ks * (N_DIM / KSPLIT);
  const int sq   = tid >> 4;       // softmax: q row 0..63
  const int kp   = tid & 15;       // softmax: key pair (2kp, 2kp+1)

  // Q frags (B-operand): qf[j][kc] = X[qb+(qh*2+j)*16+c][dq*128+kc*32+g*8..+7]
  f16x8 qf[2][4];
  #pragma unroll
  for (int j = 0; j < 2; ++j) {
    const float* qrow = X + (size_t)(qb + (qh*2 + j)*16 + c) * D_DIM + dq*128;
    #pragma unroll
    for (int kc = 0; kc < 4; ++kc) {
      float4 a = *(const float4*)(qrow + kc*32 + g*8);
      float4 b = *(const float4*)(qrow + kc*32 + g*8 + 4);
      qf[j][kc] = (f16x8){(f16)a.x,(f16)a.y,(f16)a.z,(f16)a.w,
                          (f16)b.x,(f16)b.y,(f16)b.z,(f16)b.w};
    }
  }

  f32x4 acc[4][4];   // [qt][dt] over PV d-slice wd
  #pragma unroll
  for (int qt = 0; qt < 4; ++qt)
    #pragma unroll
    for (int dt = 0; dt < 4; ++dt) acc[qt][dt] = (f32x4){0.f,0.f,0.f,0.f};

  float m_run = -1.0e30f, l_run = 0.0f;

  for (int it = 0; it < ITERS; ++it) {
    const size_t kbase = key0 + (size_t)it * KB;

    // ---- issue V loads early: latency hides under phase A/B (drained at B1
    // along with the ak loads anyway; consumed in phase C)
    const f16* vbase = W2 + (key0/KB + it) * (size_t)(D_DIM*KB);
    f16x8 bv[4];
    #pragma unroll
    for (int dt = 0; dt < 4; ++dt)
      bv[dt] = *(const f16x8*)(vbase + (size_t)(wd + dt*16 + c)*KB + g*8);

    // ---- phase A: QK^T partials, d-slice dq*128, q-tiles qh*2..qh*2+1
    #pragma unroll
    for (int kt = 0; kt < 2; ++kt) {
      f16x8 ak[4];
      #pragma unroll
      for (int kc = 0; kc < 4; ++kc)
        ak[kc] = *(const f16x8*)(E16 + (kbase + kt*16 + c)*D_DIM + dq*128 + kc*32 + g*8);
      f32x4 s0 = (f32x4){0.f,0.f,0.f,0.f};
      f32x4 s1 = (f32x4){0.f,0.f,0.f,0.f};
      #pragma unroll
      for (int kc = 0; kc < 4; ++kc) {
        s0 = __builtin_amdgcn_mfma_f32_16x16x32_f16(ak[kc], qf[0][kc], s0, 0, 0, 0);
        s1 = __builtin_amdgcn_mfma_f32_16x16x32_f16(ak[kc], qf[1][kc], s1, 0, 0, 0);
      }
      const int q0 = (qh*2 + 0)*16 + c;
      const int q1 = (qh*2 + 1)*16 + c;
      *(f32x4*)&L.Spart[dq][q0][SWZ(q0, kt*16 + g*4)] = s0;
      *(f32x4*)&L.Spart[dq][q1][SWZ(q1, kt*16 + g*4)] = s1;
    }
    __syncthreads();                               // B1

    // ---- phase B: 8-way d-slice reduce + online softmax (16 thr per q row)
    f32x2 sv = (f32x2){0.f, 0.f};
    #pragma unroll
    for (int d8 = 0; d8 < 8; ++d8)
      sv += *(const f32x2*)&L.Spart[d8][sq][SWZ(sq, 2*kp)];
    float tm = fmaxf(sv[0], sv[1]);
    tm = fmaxf(tm, __shfl_xor(tm, 1));
    tm = fmaxf(tm, __shfl_xor(tm, 2));
    tm = fmaxf(tm, __shfl_xor(tm, 4));
    tm = fmaxf(tm, __shfl_xor(tm, 8));
    // T13 defer-max: only raise m when tile max exceeds it by >8
    const bool upd = tm > m_run + 8.0f;
    const float mn = upd ? tm : m_run;
    const float scale = upd ? __expf(m_run - mn) : 1.0f;
    float p0 = __expf(sv[0] - mn), p1 = __expf(sv[1] - mn);
    *(f16x2*)&L.P[sq][2*kp] = (f16x2){(f16)p0, (f16)p1};
    float ps = p0 + p1;
    ps += __shfl_xor(ps, 1);
    ps += __shfl_xor(ps, 2);
    ps += __shfl_xor(ps, 4);
    ps += __shfl_xor(ps, 8);
    l_run = l_run * scale + ps;
    m_run = mn;
    if (kp == 0) L.srow[sq] = scale;
    __syncthreads();                               // B2

    // ---- phase C: (gated) rescale + PV.  2 barriers/iter total:
    // Spart: A writes(i+1) after B1(i+1) > all B reads(i) done at B2(i). OK.
    // P/srow: B writes(i+1) after B1(i+1) => every wave passed A(i+1), i.e.
    // finished C(i) reads. OK.
    #pragma unroll
    for (int qt = 0; qt < 4; ++qt) {
      f32x4 sc = *(const f32x4*)&L.srow[qt*16 + g*4];
      bool need = (sc[0]!=1.f)|(sc[1]!=1.f)|(sc[2]!=1.f)|(sc[3]!=1.f);
      if (__any(need)) {
        #pragma unroll
        for (int dt = 0; dt < 4; ++dt) {
          acc[qt][dt][0] *= sc[0]; acc[qt][dt][1] *= sc[1];
          acc[qt][dt][2] *= sc[2]; acc[qt][dt][3] *= sc[3];
        }
      }
    }
    #pragma unroll
    for (int qt = 0; qt < 4; ++qt) {
      f16x8 ap = *(const f16x8*)&L.P[qt*16 + c][g*8];
      #pragma unroll
      for (int dt = 0; dt < 4; ++dt)
        acc[qt][dt] = __builtin_amdgcn_mfma_f32_16x16x32_f16(ap, bv[dt], acc[qt][dt], 0, 0, 0);
    }
  }

  // ---- epilogue: normalized f16 partials + (m,l)
  if (kp == 0) {
    size_t qg = (size_t)qb + sq;
    ML[((size_t)ks * T_DIM + qg) * 2 + 0] = m_run;
    ML[((size_t)ks * T_DIM + qg) * 2 + 1] = l_run;
    L.linv[sq] = 1.0f / l_run;
  }
  __syncthreads();
  #pragma unroll
  for (int qt = 0; qt < 4; ++qt) {
    f32x4 li = *(const f32x4*)&L.linv[qt*16 + g*4];
    #pragma unroll
    for (int dt = 0; dt < 4; ++dt)
      #pragma unroll
      for (int r = 0; r < 4; ++r)
        O16[((size_t)ks * T_DIM + qb + qt*16 + 4*g + r) * D_DIM + wd + dt*16 + c] =
            (f16)(acc[qt][dt][r] * li[r]);
  }
}

// ---- combine: out = sum_ks w_ks * O_ks, w_ks = l_ks e^{m_ks-M} / sum l e^{m-M}
__global__ void combine(const f16* __restrict__ O16, const float* __restrict__ ML,
                        float* __restrict__ Out) {
  int q  = blockIdx.x;
  int d0 = threadIdx.x * 4;
  float m[KSPLIT], l[KSPLIT];
  float M = -1.0e30f;
  #pragma unroll
  for (int ks = 0; ks < KSPLIT; ++ks) {
    m[ks] = ML[((size_t)ks * T_DIM + q) * 2 + 0];
    l[ks] = ML[((size_t)ks * T_DIM + q) * 2 + 1];
    M = fmaxf(M, m[ks]);
  }
  float W = 0.f, wk[KSPLIT];
  #pragma unroll
  for (int ks = 0; ks < KSPLIT; ++ks) {
    wk[ks] = l[ks] * __expf(m[ks] - M);
    W += wk[ks];
  }
  float inv = 1.0f / W;
  float o0 = 0.f, o1 = 0.f, o2 = 0.f, o3 = 0.f;
  #pragma unroll
  for (int ks = 0; ks < KSPLIT; ++ks) {
    f16x4 v = *(const f16x4*)(O16 + ((size_t)ks * T_DIM + q) * D_DIM + d0);
    o0 += wk[ks] * (float)v[0];
    o1 += wk[ks] * (float)v[1];
    o2 += wk[ks] * (float)v[2];
    o3 += wk[ks] * (float)v[3];
  }
  float4 o = {o0 * inv, o1 * inv, o2 * inv, o3 * inv};
  *(float4*)(Out + (size_t)q * D_DIM + d0) = o;
}

// ---- fallback (tiny ws): one wave per q row, fp32 streaming online softmax
__global__ void cboe_naive(const float* __restrict__ X, const float* __restrict__ E,
                           float* __restrict__ Out) {
  int row  = blockIdx.x * 4 + (threadIdx.x >> 6);
  int lane = threadIdx.x & 63;
  float xq[16], acc[16];
  #pragma unroll
  for (int j = 0; j < 16; ++j) {
    xq[j] = X[(size_t)row * D_DIM + lane*16 + j];
    acc[j] = 0.f;
  }
  float m = -1.0e30f, l = 0.f;
  for (int key = 0; key < N_DIM; ++key) {
    const float* er = E + (size_t)key * D_DIM + lane*16;
    float ev[16];
    float s = 0.f;
    #pragma unroll
    for (int j = 0; j < 16; ++j) { ev[j] = er[j]; s += xq[j] * ev[j]; }
    #pragma unroll
    for (int sh = 1; sh < 64; sh <<= 1) s += __shfl_xor(s, sh);
    float mn = fmaxf(m, s);
    float sc = __expf(m - mn);
    float p  = __expf(s - mn);
    l = l * sc + p;
    #pragma unroll
    for (int j = 0; j < 16; ++j) acc[j] = acc[j] * sc + p * ev[j];
    m = mn;
  }
  #pragma unroll
  for (int j = 0; j < 16; ++j)
    Out[(size_t)row * D_DIM + lane*16 + j] = acc[j] / l;
}

extern "C" void kernel_launch(void* const* d_in, const int* in_sizes, int n_in,
                              void* d_out, int out_size, void* d_ws, size_t ws_size,
                              hipStream_t stream) {
  const float* X  = (const float*)d_in[0];
  const float* Eg = (const float*)d_in[1];
  float* Out = (float*)d_out;

  const size_t szE16 = (size_t)N_DIM * D_DIM * sizeof(f16);            // 64 MiB
  const size_t szW2  = (size_t)NKB_TOT * D_DIM * KB * sizeof(f16);     // 64 MiB
  const size_t szO16 = (size_t)KSPLIT * T_DIM * D_DIM * sizeof(f16);   // 32 MiB
  const size_t szML  = (size_t)KSPLIT * T_DIM * 2 * sizeof(float);     // 128 KiB
  const size_t need  = szE16 + szW2 + szO16 + szML;

  if (!d_ws || ws_size < need) {
    cboe_naive<<<dim3(T_DIM/4), dim3(256), 0, stream>>>(X, Eg, Out);
    return;
  }

  char* p = (char*)d_ws;
  f16*   E16 = (f16*)p;   p += szE16;
  f16*   W2  = (f16*)p;   p += szW2;
  f16*   O16 = (f16*)p;   p += szO16;
  float* ML  = (float*)p;

  e16_build<<<dim3((N_DIM * D_DIM) / (256 * 8)), dim3(256), 0, stream>>>(Eg, E16);
  w2_build<<<dim3(NKB_TOT * 4), dim3(256), 0, stream>>>(Eg, W2);

  const int shmem = (int)sizeof(Lds);
  hipFuncSetAttribute(reinterpret_cast<const void*>(&cboe_attn),
                      hipFuncAttributeMaxDynamicSharedMemorySize, shmem);
  cboe_attn<<<dim3((T_DIM / QB) * KSPLIT), dim3(1024), shmem, stream>>>(
      X, E16, W2, O16, ML);
  combine<<<dim3(T_DIM), dim3(256), 0, stream>>>(O16, ML, Out);
}

// Round 5
// 2477.894 us; speedup vs baseline: 1.5379x; 1.5379x over previous
//
#include <hip/hip_runtime.h>
#include <stdint.h>

#define T_DIM 4096
#define N_DIM 32768
#define D_DIM 1024
#define QB 64
#define KB 32
#define KSPLIT 4
#define ITERS (N_DIM / KSPLIT / KB)   // 256 iterations per block
#define NKB_TOT (N_DIM / KB)          // 1024 key-blocks total

typedef _Float16 f16;
typedef _Float16 f16x8 __attribute__((ext_vector_type(8)));
typedef _Float16 f16x4 __attribute__((ext_vector_type(4)));
typedef _Float16 f16x2 __attribute__((ext_vector_type(2)));
typedef float f32x4 __attribute__((ext_vector_type(4)));
typedef float f32x2 __attribute__((ext_vector_type(2)));

// XOR bits 2-3 of k-index with q's bits 2-3: b128 Spart ops spread bank-quads
#define SWZ(q, k0) ((k0) ^ ((((q) >> 2) & 3) << 2))

struct __align__(16) Lds {
  float Spart[8][64][40];  // 80 KiB : summed partial scores [slot][q][k swz]
  f16   P[64][40];         //  5 KiB : P[q][k]
  float srow[64];          // per-q rescale factor for this iter
  float linv[64];          // epilogue 1/l
};                         // ~85.5 KiB

// ---- precompute: E (fp32 row-major) -> E16 (fp16 row-major)
__global__ void e16_build(const float* __restrict__ E, f16* __restrict__ E16) {
  size_t i8 = (size_t)(blockIdx.x * 256 + threadIdx.x) * 8;
  float4 a = *(const float4*)(E + i8);
  float4 b = *(const float4*)(E + i8 + 4);
  f16x8 v = {(f16)a.x,(f16)a.y,(f16)a.z,(f16)a.w,
             (f16)b.x,(f16)b.y,(f16)b.z,(f16)b.w};
  *(f16x8*)(E16 + i8) = v;
}

// ---- precompute: W2[kb][d][k] = fp16(E[kb*32+k][d])  (key-major V tiles)
__global__ void w2_build(const float* __restrict__ E, f16* __restrict__ W2) {
  int kb = blockIdx.x >> 2;
  int dg = blockIdx.x & 3;
  int d  = dg * 256 + threadIdx.x;
  for (int kq = 0; kq < 4; ++kq) {
    int k0 = kq * 8;
    f16x8 v;
    #pragma unroll
    for (int j = 0; j < 8; ++j)
      v[j] = (f16)E[(size_t)(kb*32 + k0 + j) * D_DIM + d];
    *(f16x8*)(W2 + (size_t)kb * (D_DIM*KB) + (size_t)d*KB + k0) = v;
  }
}

// 1024 threads = 16 waves. Wave w owns the 64-wide d-slice [w*64, w*64+64)
// for BOTH QK^T partials and PV accumulation -> zero duplication of K/V
// reads (64 KB K + 64 KB V per block-iter). 16 partials fold into 8 Spart
// slots: waves 0-7 store, B1, waves 8-15 read-add-write disjoint slots, B2,
// cooperative softmax, B3, PV. Frag maps (verified r1-r3): A row=lane&15,
// k=(lane>>4)*8+j; B col=lane&15; C row=4*(lane>>4)+r, col=lane&15.
__global__ __launch_bounds__(1024)
void cboe_attn(const float* __restrict__ X, const f16* __restrict__ E16,
               const f16* __restrict__ W2, f16* __restrict__ O16,
               float* __restrict__ ML)
{
  extern __shared__ char smem_raw[];
  Lds& L = *reinterpret_cast<Lds*>(smem_raw);
  const int tid  = threadIdx.x;
  const int lane = tid & 63;
  const int w    = tid >> 6;       // wave 0..15
  const int c    = lane & 15;
  const int g    = lane >> 4;      // 0..3
  const int wd   = w * 64;         // this wave's d-slice (QK and PV)
  const int sp   = w & 7;          // Spart slot
  const bool second = (w >= 8);    // RMW half

  const int qtile = blockIdx.x & 63;
  const int ks    = blockIdx.x >> 6;         // r2-style natural chunking
  const int qb    = qtile * QB;
  const size_t key0 = (size_t)ks * (N_DIM / KSPLIT);
  const int sq   = tid >> 4;       // softmax: q row 0..63
  const int kp   = tid & 15;       // softmax: key pair (2kp, 2kp+1)

  // Q frags (B-operand): qf[qt][kc] = X[qb+qt*16+c][wd+kc*32+g*8 ..+7]
  f16x8 qf[4][2];
  #pragma unroll
  for (int qt = 0; qt < 4; ++qt) {
    const float* qrow = X + (size_t)(qb + qt*16 + c) * D_DIM + wd;
    #pragma unroll
    for (int kc = 0; kc < 2; ++kc) {
      float4 a = *(const float4*)(qrow + kc*32 + g*8);
      float4 b = *(const float4*)(qrow + kc*32 + g*8 + 4);
      qf[qt][kc] = (f16x8){(f16)a.x,(f16)a.y,(f16)a.z,(f16)a.w,
                           (f16)b.x,(f16)b.y,(f16)b.z,(f16)b.w};
    }
  }

  f32x4 acc[4][4];   // [qt][dt] over this wave's 64-d slice
  #pragma unroll
  for (int qt = 0; qt < 4; ++qt)
    #pragma unroll
    for (int dt = 0; dt < 4; ++dt) acc[qt][dt] = (f32x4){0.f,0.f,0.f,0.f};

  float m_run = -1.0e30f, l_run = 0.0f;   // per (sq,kp), replicated x16

  for (int it = 0; it < ITERS; ++it) {
    const size_t kbase = key0 + (size_t)it * KB;

    // ---- phase A: QK^T partials over this wave's 64-d slice, all 4 q-tiles
    f32x4 sacc[2][4];
    #pragma unroll
    for (int kt = 0; kt < 2; ++kt) {
      f16x8 ak[2];
      #pragma unroll
      for (int kc = 0; kc < 2; ++kc)
        ak[kc] = *(const f16x8*)(E16 + (kbase + kt*16 + c)*D_DIM + wd + kc*32 + g*8);
      #pragma unroll
      for (int qt = 0; qt < 4; ++qt) {
        f32x4 s = (f32x4){0.f,0.f,0.f,0.f};
        s = __builtin_amdgcn_mfma_f32_16x16x32_f16(ak[0], qf[qt][0], s, 0, 0, 0);
        s = __builtin_amdgcn_mfma_f32_16x16x32_f16(ak[1], qf[qt][1], s, 0, 0, 0);
        sacc[kt][qt] = s;
      }
      if (!second) {
        #pragma unroll
        for (int qt = 0; qt < 4; ++qt) {
          int q = qt*16 + c;
          *(f32x4*)&L.Spart[sp][q][SWZ(q, kt*16 + g*4)] = sacc[kt][qt];
        }
      }
    }
    __syncthreads();                               // B1

    // ---- RMW fold: waves 8-15 add their partials into slot sp (disjoint)
    if (second) {
      #pragma unroll
      for (int kt = 0; kt < 2; ++kt)
        #pragma unroll
        for (int qt = 0; qt < 4; ++qt) {
          int q = qt*16 + c;
          f32x4* p = (f32x4*)&L.Spart[sp][q][SWZ(q, kt*16 + g*4)];
          *p += sacc[kt][qt];
        }
    }
    // V loads issue here: latency hides under softmax phase
    f16x8 bv[4];
    {
      const f16* vbase = W2 + (key0/KB + it) * (size_t)(D_DIM*KB);
      #pragma unroll
      for (int dt = 0; dt < 4; ++dt)
        bv[dt] = *(const f16x8*)(vbase + (size_t)(wd + dt*16 + c)*KB + g*8);
    }
    __syncthreads();                               // B2

    // ---- softmax: 16 threads per q row, f32x2 per thread
    f32x2 sv = (f32x2){0.f, 0.f};
    #pragma unroll
    for (int d8 = 0; d8 < 8; ++d8)
      sv += *(const f32x2*)&L.Spart[d8][sq][SWZ(sq, 2*kp)];
    float tm = fmaxf(sv[0], sv[1]);
    tm = fmaxf(tm, __shfl_xor(tm, 1));
    tm = fmaxf(tm, __shfl_xor(tm, 2));
    tm = fmaxf(tm, __shfl_xor(tm, 4));
    tm = fmaxf(tm, __shfl_xor(tm, 8));
    // T13 defer-max
    const bool upd = tm > m_run + 8.0f;
    const float mn = upd ? tm : m_run;
    const float scale = upd ? __expf(m_run - mn) : 1.0f;
    float p0 = __expf(sv[0] - mn), p1 = __expf(sv[1] - mn);
    *(f16x2*)&L.P[sq][2*kp] = (f16x2){(f16)p0, (f16)p1};
    float ps = p0 + p1;
    ps += __shfl_xor(ps, 1);
    ps += __shfl_xor(ps, 2);
    ps += __shfl_xor(ps, 4);
    ps += __shfl_xor(ps, 8);
    l_run = l_run * scale + ps;
    m_run = mn;
    if (kp == 0) L.srow[sq] = scale;
    __syncthreads();                               // B3

    // ---- phase C: (gated) rescale + PV over this wave's 64-d slice.
    // Hazards: P/srow(i) read here, rewritten only after B2(i+1) -> safe.
    // Spart(i+1) written in A(i+1) (post-C, same inter-barrier region) but
    // softmax reads of Spart(i) completed at B3(i) -> safe.
    #pragma unroll
    for (int qt = 0; qt < 4; ++qt) {
      f32x4 sc = *(const f32x4*)&L.srow[qt*16 + g*4];
      bool need = (sc[0]!=1.f)|(sc[1]!=1.f)|(sc[2]!=1.f)|(sc[3]!=1.f);
      if (__any(need)) {
        #pragma unroll
        for (int dt = 0; dt < 4; ++dt) {
          acc[qt][dt][0] *= sc[0]; acc[qt][dt][1] *= sc[1];
          acc[qt][dt][2] *= sc[2]; acc[qt][dt][3] *= sc[3];
        }
      }
    }
    #pragma unroll
    for (int qt = 0; qt < 4; ++qt) {
      f16x8 ap = *(const f16x8*)&L.P[qt*16 + c][g*8];
      #pragma unroll
      for (int dt = 0; dt < 4; ++dt)
        acc[qt][dt] = __builtin_amdgcn_mfma_f32_16x16x32_f16(ap, bv[dt], acc[qt][dt], 0, 0, 0);
    }
  }

  // ---- epilogue: normalized f16 partials + (m,l)
  if (kp == 0) {
    size_t qg = (size_t)qb + sq;
    ML[((size_t)ks * T_DIM + qg) * 2 + 0] = m_run;
    ML[((size_t)ks * T_DIM + qg) * 2 + 1] = l_run;
    L.linv[sq] = 1.0f / l_run;
  }
  __syncthreads();
  #pragma unroll
  for (int qt = 0; qt < 4; ++qt) {
    f32x4 li = *(const f32x4*)&L.linv[qt*16 + g*4];
    #pragma unroll
    for (int dt = 0; dt < 4; ++dt)
      #pragma unroll
      for (int r = 0; r < 4; ++r)
        O16[((size_t)ks * T_DIM + qb + qt*16 + 4*g + r) * D_DIM + wd + dt*16 + c] =
            (f16)(acc[qt][dt][r] * li[r]);
  }
}

// ---- combine: out = sum_ks w_ks * O_ks, w_ks = l_ks e^{m_ks-M} / sum l e^{m-M}
__global__ void combine(const f16* __restrict__ O16, const float* __restrict__ ML,
                        float* __restrict__ Out) {
  int q  = blockIdx.x;
  int d0 = threadIdx.x * 4;
  float m[KSPLIT], l[KSPLIT];
  float M = -1.0e30f;
  #pragma unroll
  for (int ks = 0; ks < KSPLIT; ++ks) {
    m[ks] = ML[((size_t)ks * T_DIM + q) * 2 + 0];
    l[ks] = ML[((size_t)ks * T_DIM + q) * 2 + 1];
    M = fmaxf(M, m[ks]);
  }
  float W = 0.f, wk[KSPLIT];
  #pragma unroll
  for (int ks = 0; ks < KSPLIT; ++ks) {
    wk[ks] = l[ks] * __expf(m[ks] - M);
    W += wk[ks];
  }
  float inv = 1.0f / W;
  float o0 = 0.f, o1 = 0.f, o2 = 0.f, o3 = 0.f;
  #pragma unroll
  for (int ks = 0; ks < KSPLIT; ++ks) {
    f16x4 v = *(const f16x4*)(O16 + ((size_t)ks * T_DIM + q) * D_DIM + d0);
    o0 += wk[ks] * (float)v[0];
    o1 += wk[ks] * (float)v[1];
    o2 += wk[ks] * (float)v[2];
    o3 += wk[ks] * (float)v[3];
  }
  float4 o = {o0 * inv, o1 * inv, o2 * inv, o3 * inv};
  *(float4*)(Out + (size_t)q * D_DIM + d0) = o;
}

// ---- fallback (tiny ws): one wave per q row, fp32 streaming online softmax
__global__ void cboe_naive(const float* __restrict__ X, const float* __restrict__ E,
                           float* __restrict__ Out) {
  int row  = blockIdx.x * 4 + (threadIdx.x >> 6);
  int lane = threadIdx.x & 63;
  float xq[16], acc[16];
  #pragma unroll
  for (int j = 0; j < 16; ++j) {
    xq[j] = X[(size_t)row * D_DIM + lane*16 + j];
    acc[j] = 0.f;
  }
  float m = -1.0e30f, l = 0.f;
  for (int key = 0; key < N_DIM; ++key) {
    const float* er = E + (size_t)key * D_DIM + lane*16;
    float ev[16];
    float s = 0.f;
    #pragma unroll
    for (int j = 0; j < 16; ++j) { ev[j] = er[j]; s += xq[j] * ev[j]; }
    #pragma unroll
    for (int sh = 1; sh < 64; sh <<= 1) s += __shfl_xor(s, sh);
    float mn = fmaxf(m, s);
    float sc = __expf(m - mn);
    float p  = __expf(s - mn);
    l = l * sc + p;
    #pragma unroll
    for (int j = 0; j < 16; ++j) acc[j] = acc[j] * sc + p * ev[j];
    m = mn;
  }
  #pragma unroll
  for (int j = 0; j < 16; ++j)
    Out[(size_t)row * D_DIM + lane*16 + j] = acc[j] / l;
}

extern "C" void kernel_launch(void* const* d_in, const int* in_sizes, int n_in,
                              void* d_out, int out_size, void* d_ws, size_t ws_size,
                              hipStream_t stream) {
  const float* X  = (const float*)d_in[0];
  const float* Eg = (const float*)d_in[1];
  float* Out = (float*)d_out;

  const size_t szE16 = (size_t)N_DIM * D_DIM * sizeof(f16);            // 64 MiB
  const size_t szW2  = (size_t)NKB_TOT * D_DIM * KB * sizeof(f16);     // 64 MiB
  const size_t szO16 = (size_t)KSPLIT * T_DIM * D_DIM * sizeof(f16);   // 32 MiB
  const size_t szML  = (size_t)KSPLIT * T_DIM * 2 * sizeof(float);     // 128 KiB
  const size_t need  = szE16 + szW2 + szO16 + szML;

  if (!d_ws || ws_size < need) {
    cboe_naive<<<dim3(T_DIM/4), dim3(256), 0, stream>>>(X, Eg, Out);
    return;
  }

  char* p = (char*)d_ws;
  f16*   E16 = (f16*)p;   p += szE16;
  f16*   W2  = (f16*)p;   p += szW2;
  f16*   O16 = (f16*)p;   p += szO16;
  float* ML  = (float*)p;

  e16_build<<<dim3((N_DIM * D_DIM) / (256 * 8)), dim3(256), 0, stream>>>(Eg, E16);
  w2_build<<<dim3(NKB_TOT * 4), dim3(256), 0, stream>>>(Eg, W2);

  const int shmem = (int)sizeof(Lds);
  hipFuncSetAttribute(reinterpret_cast<const void*>(&cboe_attn),
                      hipFuncAttributeMaxDynamicSharedMemorySize, shmem);
  cboe_attn<<<dim3((T_DIM / QB) * KSPLIT), dim3(1024), shmem, stream>>>(
      X, E16, W2, O16, ML);
  combine<<<dim3(T_DIM), dim3(256), 0, stream>>>(O16, ML, Out);
}